// Round 4
// baseline (133.365 us; speedup 1.0000x reference)
//
#include <hip/hip_runtime.h>
#include <hip/hip_bf16.h>

typedef __attribute__((ext_vector_type(4))) float f32x4;
typedef __attribute__((ext_vector_type(8))) short bf16x8;

#define CS 516  // dwords per epilogue c row (512 + 4 pad -> 2-way max, free)

__device__ __forceinline__ short f2bf(float f) {
  __hip_bfloat16 h = __float2bfloat16(f);
  return __builtin_bit_cast(short, h);
}

// global_load_lds, width 16: linear LDS dest (wave base + lane*16), per-lane
// global source. Canonical m97 pattern.
#define GLD_LDS16(gp, lp)                                                    \
  __builtin_amdgcn_global_load_lds(                                          \
      (const __attribute__((address_space(1))) unsigned int*)(gp),           \
      (__attribute__((address_space(3))) unsigned int*)(lp), 16, 0, 0)

// ---------------------------------------------------------------------------
// GEMM view: C[8192 x 512] = A[8192 x 1024] * B[1024 x 512], k = j*4 + kc,
// kc -> x component {0,1,2,4}.  512 cols = [c0 of i=0..255 | c4 of i=0..255].
// Bp (ws, 1 MB): per-lane MFMA B-fragment order Bp[it][cg][lane][8 shorts].
// A_img (ws, 16 MB): bf16 A, granule (row, chunk c) = 16 B = 8 k-elems
// (j pair x comps {0,1,2,4}), stored at c' = c ^ ((row&7)<<2) so that main's
// global_load_lds (linear) + ds_read_b128 is bank-uniform.
// ---------------------------------------------------------------------------
__global__ __launch_bounds__(256) void ga_prep_B(const float* __restrict__ W,
                                                 short* __restrict__ Bp) {
  const int gid = blockIdx.x * 256 + threadIdx.x;  // 65536 = 32 it * 32 cg * 64 lane
  const int l  = gid & 63;
  const int cg = (gid >> 6) & 31;
  const int it = gid >> 11;
  const int ln = l & 15, q = l >> 4;
  const int hc = cg >> 4;                 // 0 -> c0 row, 1 -> c4 row
  const int i  = (cg & 15) * 16 + ln;
  const int j0 = it * 8 + q * 2;
  const float4* W4 = (const float4*)W;

  bf16x8 o;
#pragma unroll
  for (int jj = 0; jj < 2; ++jj) {
    const float4 wv = W4[((j0 + jj) * 256 + i) * 2];  // W[j][i][0..3]
    if (!hc) {
      o[jj * 4 + 0] = f2bf(wv.x); o[jj * 4 + 1] = f2bf(wv.y);
      o[jj * 4 + 2] = f2bf(wv.z); o[jj * 4 + 3] = 0;
    } else {
      o[jj * 4 + 0] = 0;           o[jj * 4 + 1] = f2bf(wv.z);
      o[jj * 4 + 2] = f2bf(-wv.y); o[jj * 4 + 3] = f2bf(wv.x);
    }
  }
  *(bf16x8*)&Bp[(size_t)gid * 8] = o;
}

// ---------------------------------------------------------------------------
// prep_A: streaming x (f32) -> A_img (bf16). Thread = 1 granule: reads 64 B
// coalesced (2 j's x 8 comps), writes 16 B (swizzled position within the
// row's 512 B quarter-slice -> still line-coalesced). ~84 MB @ ~6 TB/s.
// A_img layout: [row 8192][q 4][c' 32] granules of 8 shorts.
// ---------------------------------------------------------------------------
__global__ __launch_bounds__(256) void ga_prep_A(const float* __restrict__ x,
                                                 short* __restrict__ A) {
  const int g = blockIdx.x * 256 + threadIdx.x;  // 1,048,576 granules
  const int row = g >> 7, rem = g & 127;
  const int q = rem >> 5, c = rem & 31;
  const int cp = c ^ ((row & 7) << 2);
  const float4* x4 = (const float4*)x + (size_t)(row * 256 + q * 64 + c * 2) * 2;
  const float4 a0 = x4[0], a1 = x4[1], b0 = x4[2], b1 = x4[3];
  bf16x8 o;
  o[0] = f2bf(a0.x); o[1] = f2bf(a0.y); o[2] = f2bf(a0.z); o[3] = f2bf(a1.x);
  o[4] = f2bf(b0.x); o[5] = f2bf(b0.y); o[6] = f2bf(b0.z); o[7] = f2bf(b1.x);
  *(bf16x8*)&A[((size_t)row * 128 + q * 32 + cp) * 8] = o;
}

// ---------------------------------------------------------------------------
// Main: 256 blocks (32 rows x ALL 512 cols) x 1024 threads (16 waves).
// Prologue: stage ALL 64 KB of this block's A via 4x global_load_lds(16B)
// per thread + prologue B frags, ONE __syncthreads. K-loop: 32 iters,
// BARRIER-FREE: 2 ds_read_b128 (bank-uniform via baked swizzle) + 4 MFMA +
// depth-4 L2-hot B pipeline. No cvt, no shuffles, no global x.
// Epilogue: two 16-row passes via c_lds alias, nontemporal full-mv writes.
// ---------------------------------------------------------------------------
__global__ __launch_bounds__(1024, 4) void ga_mv_main(
    const short* __restrict__ A, const short* __restrict__ Bp,
    const float* __restrict__ bias, float* __restrict__ y) {
  __shared__ __align__(16) char smem[65536];
  short* lds_s = (short*)smem;
  float* c_lds = (float*)smem;  // epilogue alias (A dead by then): 16*516*4 = 33024

  const int t = threadIdx.x;
  const int bm = blockIdx.x;  // 256 blocks x 32 rows
  const int lane = t & 63, w = t >> 6;
  const int ln = lane & 15, qq = lane >> 4, lnl = lane & 7;
  const int R0 = bm * 32;

  // ---- stage A: thread t copies granule (row = t>>5, c' = t&31), each q ----
  // src: A_img[R0 + t>>5][q][t&31]; dst (linear): q*16384 + t*16 bytes.
  const short* asrc = A + ((size_t)(R0 + (t >> 5)) * 128 + (t & 31)) * 8;
#pragma unroll
  for (int q = 0; q < 4; ++q)
    GLD_LDS16(asrc + q * 256, lds_s + q * 8192 + t * 8);

  // ---- B frag pipeline (depth 4). Wave w owns cgs 2w, 2w+1 ----
  const size_t bbase = (size_t)w * 1024 + lane * 8;
  bf16x8 Bf[4][2];
#define LB(itv, b)                                                           \
  {                                                                          \
    const short* p = Bp + (size_t)(itv) * 16384 + bbase;                     \
    Bf[b][0] = *(const bf16x8*)(p);                                          \
    Bf[b][1] = *(const bf16x8*)(p + 512);                                    \
  }
  LB(0, 0);
  LB(1, 1);
  LB(2, 2);
  LB(3, 3);

  __syncthreads();  // one-time drain: A image + prologue B resident

  // ---- K loop: barrier-free ----
  f32x4 acc[2][2] = {};
  const int abase = ln * 256 + qq * 8;  // shorts: row ln * 512 B + qq * 16 B
#pragma unroll
  for (int it = 0; it < 32; ++it) {
    const int q = it >> 3, tau = it & 7;
    const short* Aq = lds_s + q * 8192 + abase + ((tau ^ lnl) << 5);
    const bf16x8 af0 = *(const bf16x8*)Aq;          // rows 0-15 of tile
    const bf16x8 af1 = *(const bf16x8*)(Aq + 4096); // rows 16-31
#pragma unroll
    for (int n = 0; n < 2; ++n) {
      acc[0][n] = __builtin_amdgcn_mfma_f32_16x16x32_bf16(af0, Bf[it & 3][n],
                                                          acc[0][n], 0, 0, 0);
      acc[1][n] = __builtin_amdgcn_mfma_f32_16x16x32_bf16(af1, Bf[it & 3][n],
                                                          acc[1][n], 0, 0, 0);
    }
    if (it + 4 < 32) LB(it + 4, it & 3);  // after use of Bf[it&3] (WAR-safe)
  }
  __syncthreads();  // all A reads done before c_lds alias writes

  // ---- epilogue: two 16-row passes; acc[ep] -> c_lds -> full-mv y writes ----
  // C/D layout: col = ln, row(within 16-tile) = qq*4 + r
  const int h = t & 1, p = (t >> 1) & 255, rh = t >> 9;
  const float4 bv = ((const float4*)bias)[p * 2 + h];
  f32x4* y4 = (f32x4*)y;

#pragma unroll
  for (int ep = 0; ep < 2; ++ep) {
    if (ep) __syncthreads();  // pass-0 reads done before pass-1 writes
#pragma unroll
    for (int n = 0; n < 2; ++n)
#pragma unroll
      for (int r = 0; r < 4; ++r)
        c_lds[(qq * 4 + r) * CS + w * 32 + n * 16 + ln] = acc[ep][n][r];
    __syncthreads();
#pragma unroll
    for (int rr = 0; rr < 8; ++rr) {
      const int row = rr * 2 + rh;
      f32x4 o;
      o[0] = bv.x; o[1] = bv.y; o[2] = bv.z; o[3] = bv.w;
      o[0] += c_lds[row * CS + h * 256 + p];  // +c0 into comp0 / +c4 into comp4
      __builtin_nontemporal_store(
          o, &y4[((size_t)(R0 + ep * 16 + row) * 256 + p) * 2 + h]);
    }
  }
}

extern "C" void kernel_launch(void* const* d_in, const int* in_sizes, int n_in,
                              void* d_out, int out_size, void* d_ws, size_t ws_size,
                              hipStream_t stream) {
  const float* x = (const float*)d_in[0];
  const float* W = (const float*)d_in[1];
  const float* bias = (const float*)d_in[2];
  float* y = (float*)d_out;
  short* Bp = (short*)d_ws;                 // 1 MB @ offset 0
  short* A = (short*)d_ws + (1 << 19);      // 16 MB A image @ offset 1 MB

  ga_prep_B<<<dim3(256), dim3(256), 0, stream>>>(W, Bp);
  ga_prep_A<<<dim3(4096), dim3(256), 0, stream>>>(x, A);
  ga_mv_main<<<dim3(256), dim3(1024), 0, stream>>>(A, Bp, bias, y);
}

// Round 5
// 129.855 us; speedup vs baseline: 1.0270x; 1.0270x over previous
//
#include <hip/hip_runtime.h>
#include <hip/hip_bf16.h>

typedef __attribute__((ext_vector_type(4))) float f32x4;
typedef __attribute__((ext_vector_type(8))) short bf16x8;
typedef __attribute__((ext_vector_type(4))) short short4v;

#define XCH 16384  // shorts per 32KB x chunk buf (32 rows x 32 j x 8 comps f32)
#define ACH 136    // shorts per A row: 32 j * 4 + 8 pad (272B = 17*16B aligned)
#define CS 516     // dwords per epilogue c row (512 + 4 pad -> 2-way max, free)

__device__ __forceinline__ short f2bf(float f) {
  __hip_bfloat16 h = __float2bfloat16(f);
  return __builtin_bit_cast(short, h);
}

// global_load_lds width 16: wave-uniform LDS base + lane*16, per-lane gsrc.
#define GLD_LDS16(gp, lp)                                                    \
  __builtin_amdgcn_global_load_lds(                                          \
      (const __attribute__((address_space(1))) unsigned int*)(gp),           \
      (__attribute__((address_space(3))) unsigned int*)(lp), 16, 0, 0)

// Counted vmcnt (T4): literal N derived from the exact issue schedule below.
// Extra loads hoisted BEFORE the sequence only make the wait stricter (safe);
// asm memory clobbers pin every counted batch inside its window.
#define WAITV(N)                                            \
  {                                                         \
    asm volatile("s_waitcnt vmcnt(" #N ")" ::: "memory");   \
    __builtin_amdgcn_sched_barrier(0);                      \
  }
#define BAR()                                               \
  {                                                         \
    __builtin_amdgcn_s_barrier();                           \
    __builtin_amdgcn_sched_barrier(0);                      \
  }
#define QBAR()                                              \
  {                                                         \
    asm volatile("s_waitcnt lgkmcnt(0)" ::: "memory");      \
    __builtin_amdgcn_sched_barrier(0);                      \
    __builtin_amdgcn_s_barrier();                           \
    __builtin_amdgcn_sched_barrier(0);                      \
  }

// ---------------------------------------------------------------------------
// GEMM view: C[8192 x 512] = A[8192 x 1024] * B[1024 x 512], k = j*4 + kc,
// kc -> x component {0,1,2,4}.  512 cols = [c0 of i=0..255 | c4 of i=0..255].
// Bp (ws, 1 MB): per-lane MFMA B-fragment order Bp[it][cg][lane][8 shorts].
// ---------------------------------------------------------------------------
__global__ __launch_bounds__(256) void ga_prep_B(const float* __restrict__ W,
                                                 short* __restrict__ Bp) {
  const int gid = blockIdx.x * 256 + threadIdx.x;  // 65536 = 32 it * 32 cg * 64 lane
  const int l  = gid & 63;
  const int cg = (gid >> 6) & 31;
  const int it = gid >> 11;
  const int ln = l & 15, q = l >> 4;
  const int hc = cg >> 4;                 // 0 -> c0 row, 1 -> c4 row
  const int i  = (cg & 15) * 16 + ln;
  const int j0 = it * 8 + q * 2;
  const float4* W4 = (const float4*)W;

  bf16x8 o;
#pragma unroll
  for (int jj = 0; jj < 2; ++jj) {
    const float4 wv = W4[((j0 + jj) * 256 + i) * 2];  // W[j][i][0..3]
    if (!hc) {
      o[jj * 4 + 0] = f2bf(wv.x); o[jj * 4 + 1] = f2bf(wv.y);
      o[jj * 4 + 2] = f2bf(wv.z); o[jj * 4 + 3] = 0;
    } else {
      o[jj * 4 + 0] = 0;           o[jj * 4 + 1] = f2bf(wv.z);
      o[jj * 4 + 2] = f2bf(-wv.y); o[jj * 4 + 3] = f2bf(wv.x);
    }
  }
  *(bf16x8*)&Bp[(size_t)gid * 8] = o;
}

// ---------------------------------------------------------------------------
// Main: 256 blocks (32 rows x ALL 512 cols) x 1024 threads (16 waves), fused.
// x streamed f32 -> LDS via global_load_lds into a 3-deep rotating 32KB chunk
// buffer (8 chunks of 32 j), issued 3 chunks ahead: ~96KB/CU in flight vs the
// ~9KB Little's-law requirement at 900cy HBM latency. Per chunk:
//   WAITV(Wc) BAR          <- own gld(c) complete, publish to all waves
//   PROC: LDS f32 granule -> 4x f2bf -> A-chunk (no shuffles)  QBAR
//   issue gld(c+3)          <- xbuf[c%3] safe: all PROC(c) reads done at QBAR
//   MFMA: 4 iters x {2 ds_read_b128 + 4 MFMA} + depth-4 L2-hot B pipeline
// vmcnt literals (2 gld/chunk, 8 LB-loads/chunk, issue order
// [g0 g1 g2 L][g3 L][g4 L][g5 L][g6 L][g7 L][L][L]):
//   W(c) = issued_before_wait - pos_end(g(c)) = {12,20,28,28,28,28,26,24}.
// Epilogue: two 16-row passes via c_lds alias, nontemporal full-mv writes.
// ---------------------------------------------------------------------------
__global__ __launch_bounds__(1024, 4) void ga_mv_main(
    const float* __restrict__ x, const short* __restrict__ Bp,
    const float* __restrict__ bias, float* __restrict__ y) {
  __shared__ __align__(16) char smem[107008];  // 3*32KB x + 8704B A
  short* xb0 = (short*)smem;
  short* xb1 = (short*)smem + XCH;
  short* xb2 = (short*)smem + 2 * XCH;
  short* Ab  = (short*)smem + 3 * XCH;
  float* c_lds = (float*)smem;  // epilogue alias: 16*516*4 = 33024 B

  const int t = threadIdx.x;
  const int lane = t & 63, w = t >> 6;
  const int ln = lane & 15, qq = lane >> 4;
  const int R0 = blockIdx.x * 32;

  // ---- x staging: wave w stages rows {w, 16+w}; lane l -> j = l>>1, half = l&1
  const float* xs0 = x + (size_t)(R0 + w) * 2048 + (lane >> 1) * 8 + (lane & 1) * 4;
  const float* xs1 = x + (size_t)(R0 + 16 + w) * 2048 + (lane >> 1) * 8 + (lane & 1) * 4;
  const int xd0 = w * 512 + lane * 8;         // LDS short offset, row w
  const int xd1 = (16 + w) * 512 + lane * 8;  // row 16+w

#define XB(c) ((c) % 3 == 0 ? xb0 : ((c) % 3 == 1 ? xb1 : xb2))
#define GLDC(c)                                  \
  {                                              \
    GLD_LDS16(xs0 + (c) * 256, XB(c) + xd0);     \
    GLD_LDS16(xs1 + (c) * 256, XB(c) + xd1);     \
  }

  // ---- PROC: thread t owns granule (row = t>>5, j = t&31) of the chunk ----
  const int prow = t >> 5, pj = t & 31;
#define PROCC(c)                                                       \
  {                                                                    \
    const float* xp = (const float*)XB(c) + prow * 256 + pj * 8;       \
    const f32x4 v = *(const f32x4*)xp;                                 \
    const float v4 = xp[4];                                            \
    short4v a;                                                         \
    a[0] = f2bf(v[0]); a[1] = f2bf(v[1]);                              \
    a[2] = f2bf(v[2]); a[3] = f2bf(v4);                                \
    *(short4v*)&Ab[prow * ACH + pj * 4] = a;                           \
  }

  // ---- B frag pipeline (depth 4). Wave w owns cgs 2w, 2w+1 ----
  const size_t bbase = (size_t)w * 1024 + lane * 8;
  bf16x8 Bf[4][2];
#define LB(itv, b)                                                     \
  {                                                                    \
    const short* p = Bp + (size_t)(itv) * 16384 + bbase;               \
    Bf[b][0] = *(const bf16x8*)(p);                                    \
    Bf[b][1] = *(const bf16x8*)(p + 512);                              \
  }

  f32x4 acc[2][2] = {};

#define MFMAC(c)                                                              \
  {                                                                           \
    _Pragma("unroll")                                                         \
    for (int tau = 0; tau < 4; ++tau) {                                       \
      const int it = (c) * 4 + tau;                                           \
      const bf16x8 af0 =                                                      \
          *(const bf16x8*)&Ab[ln * ACH + (tau * 8 + qq * 2) * 4];             \
      const bf16x8 af1 =                                                      \
          *(const bf16x8*)&Ab[(16 + ln) * ACH + (tau * 8 + qq * 2) * 4];      \
      _Pragma("unroll")                                                       \
      for (int n = 0; n < 2; ++n) {                                           \
        acc[0][n] = __builtin_amdgcn_mfma_f32_16x16x32_bf16(af0, Bf[it & 3][n], \
                                                            acc[0][n], 0, 0, 0); \
        acc[1][n] = __builtin_amdgcn_mfma_f32_16x16x32_bf16(af1, Bf[it & 3][n], \
                                                            acc[1][n], 0, 0, 0); \
      }                                                                       \
      if (it + 4 < 32) LB(it + 4, it & 3);                                    \
    }                                                                         \
  }

  // ---- prologue: 3 x-chunks + 4 B-frag batches in flight ----
  GLDC(0);
  GLDC(1);
  GLDC(2);
  LB(0, 0);
  LB(1, 1);
  LB(2, 2);
  LB(3, 3);

#define CHUNK(c, Wc)               \
  {                                \
    WAITV(Wc);                     \
    BAR();                         \
    PROCC(c);                      \
    QBAR();                        \
    if ((c) + 3 < 8) GLDC((c) + 3); \
    MFMAC(c);                      \
  }

  CHUNK(0, 12)
  CHUNK(1, 20)
  CHUNK(2, 28)
  CHUNK(3, 28)
  CHUNK(4, 28)
  CHUNK(5, 28)
  CHUNK(6, 26)
  CHUNK(7, 24)

  __syncthreads();  // full drain once; A/x dead, smem becomes c_lds

  // ---- epilogue: two 16-row passes; acc[ep] -> c_lds -> full-mv y writes ----
  // C/D layout: col = ln, row(within 16-tile) = qq*4 + r
  const int h = t & 1, p = (t >> 1) & 255, rh = t >> 9;
  const float4 bv = ((const float4*)bias)[p * 2 + h];
  f32x4* y4 = (f32x4*)y;

#pragma unroll
  for (int ep = 0; ep < 2; ++ep) {
    if (ep) __syncthreads();  // pass-0 reads done before pass-1 writes
#pragma unroll
    for (int n = 0; n < 2; ++n)
#pragma unroll
      for (int r = 0; r < 4; ++r)
        c_lds[(qq * 4 + r) * CS + w * 32 + n * 16 + ln] = acc[ep][n][r];
    __syncthreads();
#pragma unroll
    for (int rr = 0; rr < 8; ++rr) {
      const int row = rr * 2 + rh;
      f32x4 o;
      o[0] = bv.x; o[1] = bv.y; o[2] = bv.z; o[3] = bv.w;
      o[0] += c_lds[row * CS + h * 256 + p];  // +c0 into comp0 / +c4 into comp4
      __builtin_nontemporal_store(
          o, &y4[((size_t)(R0 + ep * 16 + row) * 256 + p) * 2 + h]);
    }
  }
}

extern "C" void kernel_launch(void* const* d_in, const int* in_sizes, int n_in,
                              void* d_out, int out_size, void* d_ws, size_t ws_size,
                              hipStream_t stream) {
  const float* x = (const float*)d_in[0];
  const float* W = (const float*)d_in[1];
  const float* bias = (const float*)d_in[2];
  float* y = (float*)d_out;
  short* Bp = (short*)d_ws;  // 1 MB

  ga_prep_B<<<dim3(256), dim3(256), 0, stream>>>(W, Bp);
  ga_mv_main<<<dim3(256), dim3(1024), 0, stream>>>(x, Bp, bias, y);
}

// Round 6
// 124.229 us; speedup vs baseline: 1.0735x; 1.0453x over previous
//
#include <hip/hip_runtime.h>
#include <hip/hip_bf16.h>

typedef __attribute__((ext_vector_type(4))) float f32x4;
typedef __attribute__((ext_vector_type(8))) short bf16x8;
typedef __attribute__((ext_vector_type(4))) short short4v;

#define ACH2 1048        // shorts per Ab row (256 j granules * 4 + 24 pad); stride 2096B -> 2-way max on b128 frag reads
#define AB_BYTES 67072   // 32 rows * 1048 * 2
#define XB_OFF(b) (AB_BYTES + (b) * 32768)  // 2 x 32KB rotating x buffers
#define CS 516           // dwords per epilogue c row (512 + 4 pad)

__device__ __forceinline__ short f2bf(float f) {
  __hip_bfloat16 h = __float2bfloat16(f);
  return __builtin_bit_cast(short, h);
}

// global_load_lds width 16: wave-uniform LDS base + lane*16, per-lane gsrc.
#define GLD_LDS16(gp, lp)                                                    \
  __builtin_amdgcn_global_load_lds(                                          \
      (const __attribute__((address_space(1))) unsigned int*)(gp),           \
      (__attribute__((address_space(3))) unsigned int*)(lp), 16, 0, 0)

// Counted vmcnt (T4): only phase-1 x-glds are in flight when these run.
#define WAITV(N)                                            \
  {                                                         \
    asm volatile("s_waitcnt vmcnt(" #N ")" ::: "memory");   \
    __builtin_amdgcn_sched_barrier(0);                      \
  }
#define BAR()                                               \
  {                                                         \
    __builtin_amdgcn_s_barrier();                           \
    __builtin_amdgcn_sched_barrier(0);                      \
  }
// lgkm-only barrier: LDS ops complete, vmcnt pipelines (loads AND epilogue
// stores) legally cross it.
#define QBAR()                                              \
  {                                                         \
    asm volatile("s_waitcnt lgkmcnt(0)" ::: "memory");      \
    __builtin_amdgcn_sched_barrier(0);                      \
    __builtin_amdgcn_s_barrier();                           \
    __builtin_amdgcn_sched_barrier(0);                      \
  }

// ---------------------------------------------------------------------------
// GEMM view: C[8192 x 512] = A[8192 x 1024] * B[1024 x 512], k = j*4 + kc,
// kc -> x component {0,1,2,4}.  512 cols = [c0 of i=0..255 | c4 of i=0..255].
// Bp (ws, 1 MB): per-lane MFMA B-fragment order Bp[it][cg][lane][8 shorts].
// ---------------------------------------------------------------------------
__global__ __launch_bounds__(256) void ga_prep_B(const float* __restrict__ W,
                                                 short* __restrict__ Bp) {
  const int gid = blockIdx.x * 256 + threadIdx.x;  // 65536 = 32 it * 32 cg * 64 lane
  const int l  = gid & 63;
  const int cg = (gid >> 6) & 31;
  const int it = gid >> 11;
  const int ln = l & 15, q = l >> 4;
  const int hc = cg >> 4;                 // 0 -> c0 row, 1 -> c4 row
  const int i  = (cg & 15) * 16 + ln;
  const int j0 = it * 8 + q * 2;
  const float4* W4 = (const float4*)W;

  bf16x8 o;
#pragma unroll
  for (int jj = 0; jj < 2; ++jj) {
    const float4 wv = W4[((j0 + jj) * 256 + i) * 2];  // W[j][i][0..3]
    if (!hc) {
      o[jj * 4 + 0] = f2bf(wv.x); o[jj * 4 + 1] = f2bf(wv.y);
      o[jj * 4 + 2] = f2bf(wv.z); o[jj * 4 + 3] = 0;
    } else {
      o[jj * 4 + 0] = 0;           o[jj * 4 + 1] = f2bf(wv.z);
      o[jj * 4 + 2] = f2bf(-wv.y); o[jj * 4 + 3] = f2bf(wv.x);
    }
  }
  *(bf16x8*)&Bp[(size_t)gid * 8] = o;
}

// ---------------------------------------------------------------------------
// Main: 256 blocks (32 rows x ALL 512 cols) x 1024 threads (16 waves).
// PHASE 1 (fill-shaped read): stream the block's CONTIGUOUS 256KB x slab
//   row-linearly, 8 substeps of 4 whole rows (32KB). Wave w carries one
//   contiguous 2KB quarter-row per substep (2x gld_lds16); the 16 waves
//   tile each 32KB substep contiguously, blocks tile x contiguously ->
//   the machine-wide read stream is sequential like the 6.2 TB/s fills.
//   Convert in place to a 64KB bf16 A-image (all 256 j). Counted vmcnt,
//   2-deep rotation (64KB/CU in flight).
// PHASE 2: barrier-free K-loop, 32 iters x {2 ds_read_b128 + 4 MFMA},
//   depth-4 L2-hot B pipeline. No x traffic, no barriers.
// PHASE 3: epilogue via c_lds (aliases dead x buffers) with lgkm-only
//   barriers so pass-0 nontemporal y-stores drain behind pass 1.
// ---------------------------------------------------------------------------
__global__ __launch_bounds__(1024, 4) void ga_mv_main(
    const float* __restrict__ x, const short* __restrict__ Bp,
    const float* __restrict__ bias, float* __restrict__ y) {
  __shared__ __align__(16) char smem[132608];  // 67072 Ab + 2*32768 xbuf
  short* Ab = (short*)smem;
  float* c_lds = (float*)(smem + AB_BYTES);  // 33024B, aliases xbufs (dead)

  const int t = threadIdx.x;
  const int lane = t & 63, w = t >> 6;
  const int ln = lane & 15, qq = lane >> 4;
  const int R0 = blockIdx.x * 32;

  // ---- phase-1 addressing: wave w -> row (w>>2) of each 4-row group,
  //      quarter (w&3) of that 8KB row; lane l -> 16B unit within quarter.
  const float* xsrc =
      x + (size_t)(R0 + (w >> 2)) * 2048 + ((w & 3) * 128 + lane) * 4;
  const int xdst = (w >> 2) * 4096 + (w & 3) * 1024 + lane * 8;  // shorts

#define GLDX(s)                                                  \
  {                                                              \
    const float* gp = xsrc + (s) * 8192;                         \
    short* lp = (short*)(smem + XB_OFF((s)&1)) + xdst;           \
    GLD_LDS16(gp, lp);                                           \
    GLD_LDS16(gp + 256, lp + 512);                               \
  }

  // convert: thread t owns granule (row 4s + (t>>8), j = t&255)
  const int srow = t >> 8, cj = t & 255;
#define CONV(s)                                                              \
  {                                                                          \
    const float* xp =                                                        \
        (const float*)(smem + XB_OFF((s)&1)) + srow * 2048 + cj * 8;         \
    const f32x4 v = *(const f32x4*)xp;                                       \
    const float v4 = xp[4];                                                  \
    short4v a;                                                               \
    a[0] = f2bf(v[0]); a[1] = f2bf(v[1]);                                    \
    a[2] = f2bf(v[2]); a[3] = f2bf(v4);                                      \
    *(short4v*)&Ab[(4 * (s) + srow) * ACH2 + cj * 4] = a;                    \
  }

  // substep: own gld(s) landed -> publish -> convert -> converts done ->
  // reuse xbuf[s&1] for gld(s+2). 2 glds/wave/substep => WAITV literals
  // {2,2,2,2,2,2,2,0}.
#define SUBSTEP(s, Wc)             \
  {                                \
    WAITV(Wc);                     \
    BAR();                         \
    CONV(s);                       \
    QBAR();                        \
    if ((s) + 2 < 8) GLDX((s) + 2); \
  }

  GLDX(0);
  GLDX(1);
  SUBSTEP(0, 2) SUBSTEP(1, 2) SUBSTEP(2, 2) SUBSTEP(3, 2)
  SUBSTEP(4, 2) SUBSTEP(5, 2) SUBSTEP(6, 2) SUBSTEP(7, 0)
  // all x-glds retired (W=0) -> phase 2's compiler-managed B loads see a
  // clean vmcnt slate.

  // ---- phase 2: B frag pipeline (depth 4). Wave w owns cgs 2w, 2w+1 ----
  const size_t bbase = (size_t)w * 1024 + lane * 8;
  bf16x8 Bf[4][2];
#define LB(itv, b)                                                     \
  {                                                                    \
    const short* p = Bp + (size_t)(itv) * 16384 + bbase;               \
    Bf[b][0] = *(const bf16x8*)(p);                                    \
    Bf[b][1] = *(const bf16x8*)(p + 512);                              \
  }
  LB(0, 0);
  LB(1, 1);
  LB(2, 2);
  LB(3, 3);

  f32x4 acc[2][2] = {};
#pragma unroll
  for (int it = 0; it < 32; ++it) {
    const int jo = (it * 8 + qq * 2) * 4;
    const bf16x8 af0 = *(const bf16x8*)&Ab[ln * ACH2 + jo];
    const bf16x8 af1 = *(const bf16x8*)&Ab[(16 + ln) * ACH2 + jo];
#pragma unroll
    for (int n = 0; n < 2; ++n) {
      acc[0][n] = __builtin_amdgcn_mfma_f32_16x16x32_bf16(af0, Bf[it & 3][n],
                                                          acc[0][n], 0, 0, 0);
      acc[1][n] = __builtin_amdgcn_mfma_f32_16x16x32_bf16(af1, Bf[it & 3][n],
                                                          acc[1][n], 0, 0, 0);
    }
    if (it + 4 < 32) LB(it + 4, it & 3);  // after use of Bf[it&3] (WAR-safe)
  }

  // ---- phase 3: two 16-row passes; acc[ep] -> c_lds -> full-mv y writes.
  // c_lds = xbuf region (untouched by phase 2) -> no barrier needed before
  // the first writes. lgkm-only barriers: pass-0 y-stores drain behind
  // pass 1. C/D layout: col = ln, row(within 16-tile) = qq*4 + r.
  const int h = t & 1, p = (t >> 1) & 255, rh = t >> 9;
  const float4 bv = ((const float4*)bias)[p * 2 + h];
  f32x4* y4 = (f32x4*)y;

#pragma unroll
  for (int ep = 0; ep < 2; ++ep) {
    if (ep) QBAR();  // pass-0 c_lds reads done before pass-1 writes
#pragma unroll
    for (int n = 0; n < 2; ++n)
#pragma unroll
      for (int r = 0; r < 4; ++r)
        c_lds[(qq * 4 + r) * CS + w * 32 + n * 16 + ln] = acc[ep][n][r];
    QBAR();  // all waves' c_lds writes visible
#pragma unroll
    for (int rr = 0; rr < 8; ++rr) {
      const int row = rr * 2 + rh;
      f32x4 o;
      o[0] = bv.x; o[1] = bv.y; o[2] = bv.z; o[3] = bv.w;
      o[0] += c_lds[row * CS + h * 256 + p];  // +c0 into comp0 / +c4 into comp4
      __builtin_nontemporal_store(
          o, &y4[((size_t)(R0 + ep * 16 + row) * 256 + p) * 2 + h]);
    }
  }
}

extern "C" void kernel_launch(void* const* d_in, const int* in_sizes, int n_in,
                              void* d_out, int out_size, void* d_ws, size_t ws_size,
                              hipStream_t stream) {
  const float* x = (const float*)d_in[0];
  const float* W = (const float*)d_in[1];
  const float* bias = (const float*)d_in[2];
  float* y = (float*)d_out;
  short* Bp = (short*)d_ws;  // 1 MB

  ga_prep_B<<<dim3(256), dim3(256), 0, stream>>>(W, Bp);
  ga_mv_main<<<dim3(256), dim3(1024), 0, stream>>>(x, Bp, bias, y);
}